// Round 3
// baseline (1156.283 us; speedup 1.0000x reference)
//
#include <hip/hip_runtime.h>
#include <cstdint>

// ---------------------------------------------------------------------------
// MXFP4 GPT-OSS MoE experts: dense all-expert GLU MLP.
// Round 7: gemm2 rebuilt with the SAME proven deep pipeline as gemm1:
// BM=128 x BN=128(pad 23 blocks) x BK=32, 256 thr (4 waves 2x2, wave 64x64),
// 3-slot LDS ring (48KB static -> 3 blocks/CU), distance-2 prefetch,
// vmcnt(4) + single s_barrier per K-step, setprio around MFMA cluster.
// K-split 4 -> 736 blocks, all co-resident. B-staging row-clamped at h=2879;
// epilogue h<2880 guard. gemm1 unchanged from Round 6 (310us, 878 TF).
// ---------------------------------------------------------------------------

typedef float  floatx4 __attribute__((ext_vector_type(4)));
typedef __bf16 bf16x8  __attribute__((ext_vector_type(8)));

#define E8   8
#define Hdim 2880
#define Idim 2880
#define Ttok 1024
#define R1   5760   // 2*I rows of gate_up weights
#define Gg   90     // scale groups per row (K/32)
#define K2   (E8 * Idim)   // 23040 flattened (e,i) K for GEMM2

__device__ __forceinline__ void load_lds16(const void* gptr, void* lptr) {
  __builtin_amdgcn_global_load_lds(
      (const __attribute__((address_space(1))) uint32_t*)gptr,
      (__attribute__((address_space(3))) uint32_t*)lptr, 16, 0, 0);
}

__device__ __forceinline__ uint32_t f2bf(float f) {  // RTN-even fp32->bf16
  uint32_t u = __float_as_uint(f);
  return (u + 0x7FFFu + ((u >> 16) & 1u)) >> 16;
}

__device__ __forceinline__ uint32_t perm(uint32_t hi, uint32_t lo, uint32_t sel) {
  return __builtin_amdgcn_perm(hi, lo, sel);
}

// Per-scale-group LUT: bf16 bit patterns of FP4 magnitudes 0..7 scaled by
// 2^(s-127), split into low/high bytes for v_perm lookup. Entry 0 stays 0.
struct DqLut { uint32_t Ll, Lh, Hl, Hh; };

__device__ __forceinline__ DqLut make_lut(int s) {
  uint32_t A  = ((uint32_t)(s - 127) << 7) & 0xFFFFu;
  uint32_t e1 = (0x3F00u + A) & 0xFFFFu, e2 = (0x3F80u + A) & 0xFFFFu;
  uint32_t e3 = (0x3FC0u + A) & 0xFFFFu, e4 = (0x4000u + A) & 0xFFFFu;
  uint32_t e5 = (0x4040u + A) & 0xFFFFu, e6 = (0x4080u + A) & 0xFFFFu;
  uint32_t e7 = (0x40C0u + A) & 0xFFFFu;
  uint32_t B01 = e1 << 16, B23 = e2 | (e3 << 16);
  uint32_t B45 = e4 | (e5 << 16), B67 = e6 | (e7 << 16);
  DqLut L;
  L.Ll = perm(B23, B01, 0x06040200u);
  L.Hl = perm(B23, B01, 0x07050301u);
  L.Lh = perm(B67, B45, 0x06040200u);
  L.Hh = perm(B67, B45, 0x07050301u);
  return L;
}

// 4 source dwords (1 packed byte each) -> 8 bf16 (4 dwords), interleaved order.
__device__ __forceinline__ uint4 dq8(const DqLut& L, int4 wr) {
  uint32_t p = perm((uint32_t)wr.y, (uint32_t)wr.x, 0x04000400u);
  uint32_t q = perm((uint32_t)wr.w, (uint32_t)wr.z, 0x04000400u);
  uint32_t w = perm(q, p, 0x05040100u);
  uint32_t ilo = w & 0x07070707u;
  uint32_t ihi = (w >> 4) & 0x07070707u;
  uint32_t Llo = perm(L.Lh, L.Ll, ilo);
  uint32_t Hlo = perm(L.Hh, L.Hl, ilo) | ((w << 4) & 0x80808080u);
  uint32_t Lhi = perm(L.Lh, L.Ll, ihi);
  uint32_t Hhi = perm(L.Hh, L.Hl, ihi) | (w & 0x80808080u);
  uint32_t t0 = perm(Hlo, Llo, 0x05010400u);
  uint32_t t1 = perm(Hlo, Llo, 0x07030602u);
  uint32_t t2 = perm(Hhi, Lhi, 0x05010400u);
  uint32_t t3 = perm(Hhi, Lhi, 0x07030602u);
  uint4 o;
  o.x = perm(t2, t0, 0x05040100u);
  o.y = perm(t2, t0, 0x07060302u);
  o.z = perm(t3, t1, 0x05040100u);
  o.w = perm(t3, t1, 0x07060302u);
  return o;
}

// ---------------------------------------------------------------------------
__global__ void cvt_x_kernel(const float* __restrict__ x, uint16_t* __restrict__ xb, int n) {
  int i = (blockIdx.x * 256 + threadIdx.x) * 4;
  if (i >= n) return;
  float4 v = *(const float4*)(x + i);
  ushort4 o = make_ushort4((uint16_t)f2bf(v.x), (uint16_t)f2bf(v.y),
                           (uint16_t)f2bf(v.z), (uint16_t)f2bf(v.w));
  *(ushort4*)(xb + i) = o;
}

// W1 pre-dequant: one thread per scale group, layout preserved [e][r][h].
__global__ void dq_w_kernel(const int* __restrict__ blocks, const int* __restrict__ scales,
                            uint16_t* __restrict__ wd) {
  size_t g = (size_t)blockIdx.x * 256 + threadIdx.x;
  const int4* bp = (const int4*)(blocks + g * 16);
  int4 w0 = bp[0], w1 = bp[1], w2 = bp[2], w3 = bp[3];
  DqLut L = make_lut(scales[g]);
  uint4* op = (uint4*)(wd + g * 32);
  op[0] = dq8(L, w0); op[1] = dq8(L, w1); op[2] = dq8(L, w2); op[3] = dq8(L, w3);
}

// W2 pre-dequant TRANSPOSED: [e][h][i] blocks -> [h][e*Idim + i] bf16.
__global__ void dq_w2t_kernel(const int* __restrict__ blocks, const int* __restrict__ scales,
                              uint16_t* __restrict__ wt) {
  size_t g = (size_t)blockIdx.x * 256 + threadIdx.x;
  int e  = (int)(g / ((size_t)Hdim * Gg));
  int rm = (int)(g % ((size_t)Hdim * Gg));
  int h  = rm / Gg;
  int ig = rm % Gg;
  const int4* bp = (const int4*)(blocks + g * 16);
  int4 w0 = bp[0], w1 = bp[1], w2 = bp[2], w3 = bp[3];
  DqLut L = make_lut(scales[g]);
  uint4* op = (uint4*)(wt + ((size_t)h * E8 + e) * Idim + (size_t)ig * 32);
  op[0] = dq8(L, w0); op[1] = dq8(L, w1); op[2] = dq8(L, w2); op[3] = dq8(L, w3);
}

// out[t,h] = sum_e rw[t,e] * down_bias[e,h]   (gemm2 atomicAdds on top)
__global__ void bias_init_kernel(const float* __restrict__ rw, const float* __restrict__ bias,
                                 float* __restrict__ out) {
  int t  = blockIdx.y;
  int h4 = (blockIdx.x * 256 + threadIdx.x) * 4;
  if (h4 >= Hdim) return;
  float4 s = make_float4(0.f, 0.f, 0.f, 0.f);
  #pragma unroll
  for (int e = 0; e < E8; ++e) {
    float w = rw[t * E8 + e];
    float4 b = *(const float4*)(bias + (size_t)e * Hdim + h4);
    s.x += w * b.x; s.y += w * b.y; s.z += w * b.z; s.w += w * b.w;
  }
  *(float4*)(out + (size_t)t * Hdim + h4) = s;
}

// ---------------------------------------------------------------------------
// GEMM1 deep-pipelined: BM=256 tokens x BN=128 f-rows x BK=32, 512 threads
// (8 waves, 4M x 2N, wave tile 64x64). LDS: 3-slot ring (A 16KB + B 8KB per
// slot = 72KB). Distance-2 prefetch; per K-step: vmcnt(3) -> s_barrier ->
// issue 3 global_load_lds for tile j+2 -> 8 ds_read_b128 -> 16 MFMA.
// Swizzle: granule p in LDS holds global granule p ^ ((row>>1)&3)  (rows are
// 64B, so fold row bits 1..2 into the 16B-slot index -> 2-way bank alias, free).
// Epilogue: GLU + bias, pre-multiply by rw[t,e], store bf16 to act[t][(e,i)].
__global__ __launch_bounds__(512) void gemm1_dp_kernel(
    const uint16_t* __restrict__ xb, const uint16_t* __restrict__ w1d,
    const float* __restrict__ bias, const float* __restrict__ rw,
    uint16_t* __restrict__ act) {
  extern __shared__ uint16_t smem[];          // 3*8192 (A) + 3*4096 (B) = 36864 elems
  uint16_t* sAr = smem;                       // [3][256*32]
  uint16_t* sBr = smem + 3 * 8192;            // [3][128*32]
  const int tid  = threadIdx.x;
  const int lane = tid & 63, wv = tid >> 6;
  const int wm = wv >> 1, wn = wv & 1;        // 4 M-waves x 2 N-waves
  const int col = lane & 15, quad = lane >> 4;
  const int e  = blockIdx.z;
  const int t0 = blockIdx.x * 256;
  const int i0 = blockIdx.y * 64;

  floatx4 acc[4][4] = {};

  // Staging sources (per-thread, pre-swizzled granule). granule = 8 elems=16B.
  // A: 256 rows x 4 granules = 1024 -> 2 issues of 512. B: 128x4 = 1 issue.
  const uint16_t* aSrc0;
  const uint16_t* aSrc1;
  const uint16_t* bSrc;
  {
    int L0 = tid;            // issue 0: rows 0..127
    int r0 = L0 >> 2;
    int g0 = (L0 & 3) ^ ((r0 >> 1) & 3);
    aSrc0 = xb + (size_t)(t0 + r0) * Hdim + g0 * 8;
    int L1 = 512 + tid;      // issue 1: rows 128..255
    int r1 = L1 >> 2;
    int g1 = (L1 & 3) ^ ((r1 >> 1) & 3);
    aSrc1 = xb + (size_t)(t0 + r1) * Hdim + g1 * 8;
    int rb = tid >> 2;       // B rows 0..127 (deinterleaved gate/up blocks)
    int gb = (tid & 3) ^ ((rb >> 1) & 3);
    int orig = 2 * (((rb >> 6) << 5) + (rb & 31)) + ((rb >> 5) & 1);
    bSrc = w1d + ((size_t)e * R1 + 2 * i0 + orig) * Hdim + gb * 8;
  }
  // Wave-uniform LDS dst offsets (elems) within a slot; DMA adds lane*16B.
  const int aOff0 = (wv * 64) * 8;
  const int aOff1 = (512 + wv * 64) * 8;
  const int bOff  = (wv * 64) * 8;

  auto STAGE = [&](int kt, int slot) {
    const int k0 = kt * 32;
    uint16_t* A = sAr + slot * 8192;
    uint16_t* B = sBr + slot * 4096;
    load_lds16(aSrc0 + k0, A + aOff0);
    load_lds16(aSrc1 + k0, A + aOff1);
    load_lds16(bSrc + k0, B + bOff);
  };

  STAGE(0, 0);
  STAGE(1, 1);

  int sr = 0;  // read slot = j % 3
  for (int j = 0; j < 90; ++j) {
    // Drain ONLY tile j (own 3 loads); tiles j+1, j+2 stay in flight.
    asm volatile("s_waitcnt vmcnt(3)" ::: "memory");
    __builtin_amdgcn_s_barrier();          // now ALL waves' tile-j DMA landed
    asm volatile("" ::: "memory");         // pin reads below the barrier
    int js = j + 2; if (js > 89) js = 89;  // clamped tail restage (harmless)
    int sw = sr + 2; if (sw >= 3) sw -= 3; // slot of tile j-1: freed last iter
    STAGE(js, sw);

    const uint16_t* A = sAr + sr * 8192;
    const uint16_t* B = sBr + sr * 4096;
    bf16x8 af[4], bfr[4];
    #pragma unroll
    for (int fm = 0; fm < 4; ++fm) {
      int row = wm * 64 + fm * 16 + col;
      int g = quad ^ ((row >> 1) & 3);
      af[fm] = *(const bf16x8*)&A[row * 32 + g * 8];
    }
    #pragma unroll
    for (int fn = 0; fn < 4; ++fn) {
      int row = wn * 64 + fn * 16 + col;
      int g = quad ^ ((row >> 1) & 3);
      bfr[fn] = *(const bf16x8*)&B[row * 32 + g * 8];
    }
    __builtin_amdgcn_s_setprio(1);
    #pragma unroll
    for (int fm = 0; fm < 4; ++fm)
      #pragma unroll
      for (int fn = 0; fn < 4; ++fn)
        acc[fm][fn] = __builtin_amdgcn_mfma_f32_16x16x32_bf16(
            af[fm], bfr[fn], acc[fm][fn], 0, 0, 0);
    __builtin_amdgcn_s_setprio(0);
    sr = (sr + 1 == 3) ? 0 : sr + 1;
  }

  #pragma unroll
  for (int fm = 0; fm < 4; ++fm) {
    #pragma unroll
    for (int p = 0; p < 2; ++p) {
      floatx4 ga = acc[fm][p], ua = acc[fm][p + 2];
      int ig = i0 + wn * 32 + p * 16 + col;
      float bg = bias[(size_t)e * R1 + 2 * ig];
      float bu = bias[(size_t)e * R1 + 2 * ig + 1];
      #pragma unroll
      for (int r = 0; r < 4; ++r) {
        int t = t0 + wm * 64 + fm * 16 + quad * 4 + r;
        float gate = fminf(ga[r] + bg, 7.0f);
        float up   = fminf(fmaxf(ua[r] + bu, -7.0f), 7.0f);
        float glu  = gate / (1.0f + __expf(-1.702f * gate));
        float a    = rw[t * E8 + e] * (up + 1.0f) * glu;
        act[((size_t)t * E8 + e) * Idim + ig] = (uint16_t)f2bf(a);
      }
    }
  }
}

// ---------------------------------------------------------------------------
// GEMM2 deep-pipelined: M=1024 x N=2880(pad 2944) x K=23040. BM=128, BN=128,
// BK=32, K-split 4 (grid 8x23x4 = 736 blocks, all co-resident at 3 blocks/CU).
// 256 thr (4 waves 2x2, wave tile 64x64). 3-slot LDS ring (48KB static).
// Per K-step: vmcnt(4) -> s_barrier -> STAGE(j+2) -> 8 ds_read_b128 ->
// 16 MFMA (setprio-wrapped). B-staging rows clamped to h<=2879 (pad tile);
// epilogue atomicAdd guarded h<2880, onto bias_init'd out.
__global__ __launch_bounds__(256) void gemm2_dp_kernel(
    const uint16_t* __restrict__ actT, const uint16_t* __restrict__ w2t,
    float* __restrict__ out) {
  __shared__ uint16_t sAr[3][4096];
  __shared__ uint16_t sBr[3][4096];
  const int tid  = threadIdx.x;
  const int lane = tid & 63, wv = tid >> 6;
  const int wy = wv >> 1, wx = wv & 1;        // 2 M-waves x 2 N-waves
  const int col = lane & 15, quad = lane >> 4;
  const int t0 = blockIdx.x * 128;
  const int h0 = blockIdx.y * 128;            // last block: 2816..2943 (padded)
  const int kbase = blockIdx.z * (K2 / 4);    // 5760 per split

  floatx4 acc[4][4] = {};

  // Staging: A tile 128x32 = 512 granules (2 issues), B same. Swizzle: granule
  // index within row XORed by (row>>1)&3, matching gemm1's proven pattern.
  const uint16_t* aSrc0; const uint16_t* aSrc1;
  const uint16_t* bSrc0; const uint16_t* bSrc1;
  {
    int L0 = tid;        int r0 = L0 >> 2; int g0 = (L0 & 3) ^ ((r0 >> 1) & 3);
    aSrc0 = actT + (size_t)(t0 + r0) * K2 + kbase + g0 * 8;
    int L1 = 256 + tid;  int r1 = L1 >> 2; int g1 = (L1 & 3) ^ ((r1 >> 1) & 3);
    aSrc1 = actT + (size_t)(t0 + r1) * K2 + kbase + g1 * 8;
    int M0 = tid;        int s0 = M0 >> 2; int j0 = (M0 & 3) ^ ((s0 >> 1) & 3);
    int hb0 = h0 + s0; if (hb0 > Hdim - 1) hb0 = Hdim - 1;   // pad-tile clamp
    bSrc0 = w2t + (size_t)hb0 * K2 + kbase + j0 * 8;
    int M1 = 256 + tid;  int s1 = M1 >> 2; int j1 = (M1 & 3) ^ ((s1 >> 1) & 3);
    int hb1 = h0 + s1; if (hb1 > Hdim - 1) hb1 = Hdim - 1;
    bSrc1 = w2t + (size_t)hb1 * K2 + kbase + j1 * 8;
  }
  const int off0 = (wv * 64) * 8;             // issue-0 wave-uniform dst (elems)
  const int off1 = 2048 + (wv * 64) * 8;      // issue-1 dst

  auto STAGE = [&](int kt, int slot) {
    const int k0 = kt * 32;
    uint16_t* A = &sAr[slot][0];
    uint16_t* B = &sBr[slot][0];
    load_lds16(aSrc0 + k0, A + off0);
    load_lds16(aSrc1 + k0, A + off1);
    load_lds16(bSrc0 + k0, B + off0);
    load_lds16(bSrc1 + k0, B + off1);
  };

  STAGE(0, 0);
  STAGE(1, 1);

  int sr = 0;  // read slot = j % 3
  for (int j = 0; j < 180; ++j) {
    // Drain ONLY tile j (own 4 loads); tiles j+1, j+2 stay in flight.
    asm volatile("s_waitcnt vmcnt(4)" ::: "memory");
    __builtin_amdgcn_s_barrier();
    asm volatile("" ::: "memory");
    int js = j + 2; if (js > 179) js = 179;
    int sw = sr + 2; if (sw >= 3) sw -= 3;
    STAGE(js, sw);

    const uint16_t* A = &sAr[sr][0];
    const uint16_t* B = &sBr[sr][0];
    bf16x8 af[4], bfr[4];
    #pragma unroll
    for (int fm = 0; fm < 4; ++fm) {
      int row = wy * 64 + fm * 16 + col;
      int g = quad ^ ((row >> 1) & 3);
      af[fm] = *(const bf16x8*)&A[row * 32 + g * 8];
    }
    #pragma unroll
    for (int fn = 0; fn < 4; ++fn) {
      int row = wx * 64 + fn * 16 + col;
      int g = quad ^ ((row >> 1) & 3);
      bfr[fn] = *(const bf16x8*)&B[row * 32 + g * 8];
    }
    __builtin_amdgcn_s_setprio(1);
    #pragma unroll
    for (int fm = 0; fm < 4; ++fm)
      #pragma unroll
      for (int fn = 0; fn < 4; ++fn)
        acc[fm][fn] = __builtin_amdgcn_mfma_f32_16x16x32_bf16(
            af[fm], bfr[fn], acc[fm][fn], 0, 0, 0);
    __builtin_amdgcn_s_setprio(0);
    sr = (sr + 1 == 3) ? 0 : sr + 1;
  }

  #pragma unroll
  for (int fm = 0; fm < 4; ++fm)
    #pragma unroll
    for (int fn = 0; fn < 4; ++fn) {
      int h = h0 + wx * 64 + fn * 16 + col;
      if (h < Hdim) {
        #pragma unroll
        for (int r = 0; r < 4; ++r) {
          int t = t0 + wy * 64 + fm * 16 + quad * 4 + r;
          atomicAdd(out + (size_t)t * Hdim + h, acc[fm][fn][r]);
        }
      }
    }
}

// ---------------------------------------------------------------------------
extern "C" void kernel_launch(void* const* d_in, const int* in_sizes, int n_in,
                              void* d_out, int out_size, void* d_ws, size_t ws_size,
                              hipStream_t stream) {
  (void)in_sizes; (void)n_in; (void)out_size; (void)ws_size;
  const float* x        = (const float*)d_in[0];
  const float* rw       = (const float*)d_in[1];
  const int*   gub_b    = (const int*)d_in[2];
  const int*   gub_s    = (const int*)d_in[3];
  const float* gub_bias = (const float*)d_in[4];
  const int*   dwn_b    = (const int*)d_in[5];
  const int*   dwn_s    = (const int*)d_in[6];
  const float* dwn_bias = (const float*)d_in[7];
  float* out = (float*)d_out;

  // ws layout (bf16 elems): xb [T,H] | act [T, E*I] | W1d [E,R1,H] | W2t [H, E*I]
  const size_t nXb  = (size_t)Ttok * Hdim;
  const size_t nAct = (size_t)Ttok * K2;
  const size_t nW1  = (size_t)E8 * R1 * Hdim;

  uint16_t* xb  = (uint16_t*)d_ws;
  uint16_t* act = xb + nXb;
  uint16_t* w1d = act + nAct;
  uint16_t* w2t = w1d + nW1;

  static int attr_set = 0;
  if (!attr_set) {
    (void)hipFuncSetAttribute((const void*)gemm1_dp_kernel,
                              hipFuncAttributeMaxDynamicSharedMemorySize, 73728);
    attr_set = 1;
  }

  cvt_x_kernel<<<dim3((Ttok * Hdim / 4 + 255) / 256), 256, 0, stream>>>(x, xb, Ttok * Hdim);
  dq_w_kernel<<<dim3((int)((size_t)E8 * R1 * Gg / 256)), 256, 0, stream>>>(gub_b, gub_s, w1d);
  dq_w2t_kernel<<<dim3((int)((size_t)E8 * Hdim * Gg / 256)), 256, 0, stream>>>(dwn_b, dwn_s, w2t);
  bias_init_kernel<<<dim3(3, Ttok), 256, 0, stream>>>(rw, dwn_bias, out);
  gemm1_dp_kernel<<<dim3(4, 45, 8), 512, 73728, stream>>>(xb, w1d, gub_bias, rw, act);
  gemm2_dp_kernel<<<dim3(8, 23, 4), 256, 0, stream>>>(act, w2t, out);
}

// Round 4
// 1030.366 us; speedup vs baseline: 1.1222x; 1.1222x over previous
//
#include <hip/hip_runtime.h>
#include <cstdint>

// ---------------------------------------------------------------------------
// MXFP4 GPT-OSS MoE experts: dense all-expert GLU MLP.
// Round 8: gemm2 re-ported at gemm1's EXACT geometry (512 thr / 8 waves /
// BM=256 / BN=128 / BK=32 / 3-slot 72KB ring / vmcnt(3)); round-7's 4-wave
// variant starved at 5.7 waves/CU (MfmaUtil 16.7%). Grid (4,23,4), pad block
// clamped in staging + guarded in epilogue. gemm1 unchanged (310us).
// ---------------------------------------------------------------------------

typedef float  floatx4 __attribute__((ext_vector_type(4)));
typedef __bf16 bf16x8  __attribute__((ext_vector_type(8)));

#define E8   8
#define Hdim 2880
#define Idim 2880
#define Ttok 1024
#define R1   5760   // 2*I rows of gate_up weights
#define Gg   90     // scale groups per row (K/32)
#define K2   (E8 * Idim)   // 23040 flattened (e,i) K for GEMM2

__device__ __forceinline__ void load_lds16(const void* gptr, void* lptr) {
  __builtin_amdgcn_global_load_lds(
      (const __attribute__((address_space(1))) uint32_t*)gptr,
      (__attribute__((address_space(3))) uint32_t*)lptr, 16, 0, 0);
}

__device__ __forceinline__ uint32_t f2bf(float f) {  // RTN-even fp32->bf16
  uint32_t u = __float_as_uint(f);
  return (u + 0x7FFFu + ((u >> 16) & 1u)) >> 16;
}

__device__ __forceinline__ uint32_t perm(uint32_t hi, uint32_t lo, uint32_t sel) {
  return __builtin_amdgcn_perm(hi, lo, sel);
}

// Per-scale-group LUT: bf16 bit patterns of FP4 magnitudes 0..7 scaled by
// 2^(s-127), split into low/high bytes for v_perm lookup. Entry 0 stays 0.
struct DqLut { uint32_t Ll, Lh, Hl, Hh; };

__device__ __forceinline__ DqLut make_lut(int s) {
  uint32_t A  = ((uint32_t)(s - 127) << 7) & 0xFFFFu;
  uint32_t e1 = (0x3F00u + A) & 0xFFFFu, e2 = (0x3F80u + A) & 0xFFFFu;
  uint32_t e3 = (0x3FC0u + A) & 0xFFFFu, e4 = (0x4000u + A) & 0xFFFFu;
  uint32_t e5 = (0x4040u + A) & 0xFFFFu, e6 = (0x4080u + A) & 0xFFFFu;
  uint32_t e7 = (0x40C0u + A) & 0xFFFFu;
  uint32_t B01 = e1 << 16, B23 = e2 | (e3 << 16);
  uint32_t B45 = e4 | (e5 << 16), B67 = e6 | (e7 << 16);
  DqLut L;
  L.Ll = perm(B23, B01, 0x06040200u);
  L.Hl = perm(B23, B01, 0x07050301u);
  L.Lh = perm(B67, B45, 0x06040200u);
  L.Hh = perm(B67, B45, 0x07050301u);
  return L;
}

// 4 source dwords (1 packed byte each) -> 8 bf16 (4 dwords), interleaved order.
__device__ __forceinline__ uint4 dq8(const DqLut& L, int4 wr) {
  uint32_t p = perm((uint32_t)wr.y, (uint32_t)wr.x, 0x04000400u);
  uint32_t q = perm((uint32_t)wr.w, (uint32_t)wr.z, 0x04000400u);
  uint32_t w = perm(q, p, 0x05040100u);
  uint32_t ilo = w & 0x07070707u;
  uint32_t ihi = (w >> 4) & 0x07070707u;
  uint32_t Llo = perm(L.Lh, L.Ll, ilo);
  uint32_t Hlo = perm(L.Hh, L.Hl, ilo) | ((w << 4) & 0x80808080u);
  uint32_t Lhi = perm(L.Lh, L.Ll, ihi);
  uint32_t Hhi = perm(L.Hh, L.Hl, ihi) | (w & 0x80808080u);
  uint32_t t0 = perm(Hlo, Llo, 0x05010400u);
  uint32_t t1 = perm(Hlo, Llo, 0x07030602u);
  uint32_t t2 = perm(Hhi, Lhi, 0x05010400u);
  uint32_t t3 = perm(Hhi, Lhi, 0x07030602u);
  uint4 o;
  o.x = perm(t2, t0, 0x05040100u);
  o.y = perm(t2, t0, 0x07060302u);
  o.z = perm(t3, t1, 0x05040100u);
  o.w = perm(t3, t1, 0x07060302u);
  return o;
}

// ---------------------------------------------------------------------------
__global__ void cvt_x_kernel(const float* __restrict__ x, uint16_t* __restrict__ xb, int n) {
  int i = (blockIdx.x * 256 + threadIdx.x) * 4;
  if (i >= n) return;
  float4 v = *(const float4*)(x + i);
  ushort4 o = make_ushort4((uint16_t)f2bf(v.x), (uint16_t)f2bf(v.y),
                           (uint16_t)f2bf(v.z), (uint16_t)f2bf(v.w));
  *(ushort4*)(xb + i) = o;
}

// W1 pre-dequant: one thread per scale group, layout preserved [e][r][h].
__global__ void dq_w_kernel(const int* __restrict__ blocks, const int* __restrict__ scales,
                            uint16_t* __restrict__ wd) {
  size_t g = (size_t)blockIdx.x * 256 + threadIdx.x;
  const int4* bp = (const int4*)(blocks + g * 16);
  int4 w0 = bp[0], w1 = bp[1], w2 = bp[2], w3 = bp[3];
  DqLut L = make_lut(scales[g]);
  uint4* op = (uint4*)(wd + g * 32);
  op[0] = dq8(L, w0); op[1] = dq8(L, w1); op[2] = dq8(L, w2); op[3] = dq8(L, w3);
}

// W2 pre-dequant TRANSPOSED: [e][h][i] blocks -> [h][e*Idim + i] bf16.
__global__ void dq_w2t_kernel(const int* __restrict__ blocks, const int* __restrict__ scales,
                              uint16_t* __restrict__ wt) {
  size_t g = (size_t)blockIdx.x * 256 + threadIdx.x;
  int e  = (int)(g / ((size_t)Hdim * Gg));
  int rm = (int)(g % ((size_t)Hdim * Gg));
  int h  = rm / Gg;
  int ig = rm % Gg;
  const int4* bp = (const int4*)(blocks + g * 16);
  int4 w0 = bp[0], w1 = bp[1], w2 = bp[2], w3 = bp[3];
  DqLut L = make_lut(scales[g]);
  uint4* op = (uint4*)(wt + ((size_t)h * E8 + e) * Idim + (size_t)ig * 32);
  op[0] = dq8(L, w0); op[1] = dq8(L, w1); op[2] = dq8(L, w2); op[3] = dq8(L, w3);
}

// out[t,h] = sum_e rw[t,e] * down_bias[e,h]   (gemm2 atomicAdds on top)
__global__ void bias_init_kernel(const float* __restrict__ rw, const float* __restrict__ bias,
                                 float* __restrict__ out) {
  int t  = blockIdx.y;
  int h4 = (blockIdx.x * 256 + threadIdx.x) * 4;
  if (h4 >= Hdim) return;
  float4 s = make_float4(0.f, 0.f, 0.f, 0.f);
  #pragma unroll
  for (int e = 0; e < E8; ++e) {
    float w = rw[t * E8 + e];
    float4 b = *(const float4*)(bias + (size_t)e * Hdim + h4);
    s.x += w * b.x; s.y += w * b.y; s.z += w * b.z; s.w += w * b.w;
  }
  *(float4*)(out + (size_t)t * Hdim + h4) = s;
}

// ---------------------------------------------------------------------------
// GEMM1 deep-pipelined: BM=256 tokens x BN=128 f-rows x BK=32, 512 threads
// (8 waves, 4M x 2N, wave tile 64x64). LDS: 3-slot ring (A 16KB + B 8KB per
// slot = 72KB). Distance-2 prefetch; per K-step: vmcnt(3) -> s_barrier ->
// issue 3 global_load_lds for tile j+2 -> 8 ds_read_b128 -> 16 MFMA.
// Swizzle: granule p in LDS holds global granule p ^ ((row>>1)&3)  (rows are
// 64B, so fold row bits 1..2 into the 16B-slot index -> 2-way bank alias, free).
// Epilogue: GLU + bias, pre-multiply by rw[t,e], store bf16 to act[t][(e,i)].
__global__ __launch_bounds__(512) void gemm1_dp_kernel(
    const uint16_t* __restrict__ xb, const uint16_t* __restrict__ w1d,
    const float* __restrict__ bias, const float* __restrict__ rw,
    uint16_t* __restrict__ act) {
  extern __shared__ uint16_t smem[];          // 3*8192 (A) + 3*4096 (B) = 36864 elems
  uint16_t* sAr = smem;                       // [3][256*32]
  uint16_t* sBr = smem + 3 * 8192;            // [3][128*32]
  const int tid  = threadIdx.x;
  const int lane = tid & 63, wv = tid >> 6;
  const int wm = wv >> 1, wn = wv & 1;        // 4 M-waves x 2 N-waves
  const int col = lane & 15, quad = lane >> 4;
  const int e  = blockIdx.z;
  const int t0 = blockIdx.x * 256;
  const int i0 = blockIdx.y * 64;

  floatx4 acc[4][4] = {};

  // Staging sources (per-thread, pre-swizzled granule). granule = 8 elems=16B.
  // A: 256 rows x 4 granules = 1024 -> 2 issues of 512. B: 128x4 = 1 issue.
  const uint16_t* aSrc0;
  const uint16_t* aSrc1;
  const uint16_t* bSrc;
  {
    int L0 = tid;            // issue 0: rows 0..127
    int r0 = L0 >> 2;
    int g0 = (L0 & 3) ^ ((r0 >> 1) & 3);
    aSrc0 = xb + (size_t)(t0 + r0) * Hdim + g0 * 8;
    int L1 = 512 + tid;      // issue 1: rows 128..255
    int r1 = L1 >> 2;
    int g1 = (L1 & 3) ^ ((r1 >> 1) & 3);
    aSrc1 = xb + (size_t)(t0 + r1) * Hdim + g1 * 8;
    int rb = tid >> 2;       // B rows 0..127 (deinterleaved gate/up blocks)
    int gb = (tid & 3) ^ ((rb >> 1) & 3);
    int orig = 2 * (((rb >> 6) << 5) + (rb & 31)) + ((rb >> 5) & 1);
    bSrc = w1d + ((size_t)e * R1 + 2 * i0 + orig) * Hdim + gb * 8;
  }
  // Wave-uniform LDS dst offsets (elems) within a slot; DMA adds lane*16B.
  const int aOff0 = (wv * 64) * 8;
  const int aOff1 = (512 + wv * 64) * 8;
  const int bOff  = (wv * 64) * 8;

  auto STAGE = [&](int kt, int slot) {
    const int k0 = kt * 32;
    uint16_t* A = sAr + slot * 8192;
    uint16_t* B = sBr + slot * 4096;
    load_lds16(aSrc0 + k0, A + aOff0);
    load_lds16(aSrc1 + k0, A + aOff1);
    load_lds16(bSrc + k0, B + bOff);
  };

  STAGE(0, 0);
  STAGE(1, 1);

  int sr = 0;  // read slot = j % 3
  for (int j = 0; j < 90; ++j) {
    // Drain ONLY tile j (own 3 loads); tiles j+1, j+2 stay in flight.
    asm volatile("s_waitcnt vmcnt(3)" ::: "memory");
    __builtin_amdgcn_s_barrier();          // now ALL waves' tile-j DMA landed
    asm volatile("" ::: "memory");         // pin reads below the barrier
    int js = j + 2; if (js > 89) js = 89;  // clamped tail restage (harmless)
    int sw = sr + 2; if (sw >= 3) sw -= 3; // slot of tile j-1: freed last iter
    STAGE(js, sw);

    const uint16_t* A = sAr + sr * 8192;
    const uint16_t* B = sBr + sr * 4096;
    bf16x8 af[4], bfr[4];
    #pragma unroll
    for (int fm = 0; fm < 4; ++fm) {
      int row = wm * 64 + fm * 16 + col;
      int g = quad ^ ((row >> 1) & 3);
      af[fm] = *(const bf16x8*)&A[row * 32 + g * 8];
    }
    #pragma unroll
    for (int fn = 0; fn < 4; ++fn) {
      int row = wn * 64 + fn * 16 + col;
      int g = quad ^ ((row >> 1) & 3);
      bfr[fn] = *(const bf16x8*)&B[row * 32 + g * 8];
    }
    __builtin_amdgcn_s_setprio(1);
    #pragma unroll
    for (int fm = 0; fm < 4; ++fm)
      #pragma unroll
      for (int fn = 0; fn < 4; ++fn)
        acc[fm][fn] = __builtin_amdgcn_mfma_f32_16x16x32_bf16(
            af[fm], bfr[fn], acc[fm][fn], 0, 0, 0);
    __builtin_amdgcn_s_setprio(0);
    sr = (sr + 1 == 3) ? 0 : sr + 1;
  }

  #pragma unroll
  for (int fm = 0; fm < 4; ++fm) {
    #pragma unroll
    for (int p = 0; p < 2; ++p) {
      floatx4 ga = acc[fm][p], ua = acc[fm][p + 2];
      int ig = i0 + wn * 32 + p * 16 + col;
      float bg = bias[(size_t)e * R1 + 2 * ig];
      float bu = bias[(size_t)e * R1 + 2 * ig + 1];
      #pragma unroll
      for (int r = 0; r < 4; ++r) {
        int t = t0 + wm * 64 + fm * 16 + quad * 4 + r;
        float gate = fminf(ga[r] + bg, 7.0f);
        float up   = fminf(fmaxf(ua[r] + bu, -7.0f), 7.0f);
        float glu  = gate / (1.0f + __expf(-1.702f * gate));
        float a    = rw[t * E8 + e] * (up + 1.0f) * glu;
        act[((size_t)t * E8 + e) * Idim + ig] = (uint16_t)f2bf(a);
      }
    }
  }
}

// ---------------------------------------------------------------------------
// GEMM2 deep-pipelined, gemm1 geometry: M=1024 x N=2880(pad->2944) x K=23040.
// BM=256, BN=128, BK=32, K-split 4 -> grid (4,23,4)=368 blocks. 512 thr
// (8 waves, 4M x 2N, wave 64x64). 3-slot 72KB ring, distance-2 prefetch,
// vmcnt(3) + single s_barrier per K-step, setprio-wrapped MFMA. B staging
// rows clamped to h<=2879 (pad tile); epilogue atomicAdd guarded h<2880.
__global__ __launch_bounds__(512) void gemm2_dp_kernel(
    const uint16_t* __restrict__ actT, const uint16_t* __restrict__ w2t,
    float* __restrict__ out) {
  extern __shared__ uint16_t smem[];          // 3*8192 (A) + 3*4096 (B)
  uint16_t* sAr = smem;                       // [3][256*32]
  uint16_t* sBr = smem + 3 * 8192;            // [3][128*32]
  const int tid  = threadIdx.x;
  const int lane = tid & 63, wv = tid >> 6;
  const int wm = wv >> 1, wn = wv & 1;        // 4 M-waves x 2 N-waves
  const int col = lane & 15, quad = lane >> 4;
  const int t0 = blockIdx.x * 256;
  const int h0 = blockIdx.y * 128;            // last block: 2816..2943 (padded)
  const int kbase = blockIdx.z * (K2 / 4);    // 5760 per split

  floatx4 acc[4][4] = {};

  const uint16_t* aSrc0;
  const uint16_t* aSrc1;
  const uint16_t* bSrc;
  {
    int L0 = tid;            // A rows 0..127
    int r0 = L0 >> 2;
    int g0 = (L0 & 3) ^ ((r0 >> 1) & 3);
    aSrc0 = actT + (size_t)(t0 + r0) * K2 + kbase + g0 * 8;
    int L1 = 512 + tid;      // A rows 128..255
    int r1 = L1 >> 2;
    int g1 = (L1 & 3) ^ ((r1 >> 1) & 3);
    aSrc1 = actT + (size_t)(t0 + r1) * K2 + kbase + g1 * 8;
    int rb = tid >> 2;       // B rows 0..127 of w2t panel
    int gb = (tid & 3) ^ ((rb >> 1) & 3);
    int hb = h0 + rb; if (hb > Hdim - 1) hb = Hdim - 1;   // pad-tile clamp
    bSrc = w2t + (size_t)hb * K2 + kbase + gb * 8;
  }
  const int aOff0 = (wv * 64) * 8;
  const int aOff1 = (512 + wv * 64) * 8;
  const int bOff  = (wv * 64) * 8;

  auto STAGE = [&](int kt, int slot) {
    const int k0 = kt * 32;
    uint16_t* A = sAr + slot * 8192;
    uint16_t* B = sBr + slot * 4096;
    load_lds16(aSrc0 + k0, A + aOff0);
    load_lds16(aSrc1 + k0, A + aOff1);
    load_lds16(bSrc + k0, B + bOff);
  };

  STAGE(0, 0);
  STAGE(1, 1);

  int sr = 0;  // read slot = j % 3
  for (int j = 0; j < 180; ++j) {
    asm volatile("s_waitcnt vmcnt(3)" ::: "memory");
    __builtin_amdgcn_s_barrier();
    asm volatile("" ::: "memory");
    int js = j + 2; if (js > 179) js = 179;
    int sw = sr + 2; if (sw >= 3) sw -= 3;
    STAGE(js, sw);

    const uint16_t* A = sAr + sr * 8192;
    const uint16_t* B = sBr + sr * 4096;
    bf16x8 af[4], bfr[4];
    #pragma unroll
    for (int fm = 0; fm < 4; ++fm) {
      int row = wm * 64 + fm * 16 + col;
      int g = quad ^ ((row >> 1) & 3);
      af[fm] = *(const bf16x8*)&A[row * 32 + g * 8];
    }
    #pragma unroll
    for (int fn = 0; fn < 4; ++fn) {
      int row = wn * 64 + fn * 16 + col;
      int g = quad ^ ((row >> 1) & 3);
      bfr[fn] = *(const bf16x8*)&B[row * 32 + g * 8];
    }
    __builtin_amdgcn_s_setprio(1);
    #pragma unroll
    for (int fm = 0; fm < 4; ++fm)
      #pragma unroll
      for (int fn = 0; fn < 4; ++fn)
        acc[fm][fn] = __builtin_amdgcn_mfma_f32_16x16x32_bf16(
            af[fm], bfr[fn], acc[fm][fn], 0, 0, 0);
    __builtin_amdgcn_s_setprio(0);
    sr = (sr + 1 == 3) ? 0 : sr + 1;
  }

  #pragma unroll
  for (int fm = 0; fm < 4; ++fm)
    #pragma unroll
    for (int fn = 0; fn < 4; ++fn) {
      int h = h0 + wn * 64 + fn * 16 + col;
      if (h < Hdim) {
        #pragma unroll
        for (int r = 0; r < 4; ++r) {
          int t = t0 + wm * 64 + fm * 16 + quad * 4 + r;
          atomicAdd(out + (size_t)t * Hdim + h, acc[fm][fn][r]);
        }
      }
    }
}

// ---------------------------------------------------------------------------
extern "C" void kernel_launch(void* const* d_in, const int* in_sizes, int n_in,
                              void* d_out, int out_size, void* d_ws, size_t ws_size,
                              hipStream_t stream) {
  (void)in_sizes; (void)n_in; (void)out_size; (void)ws_size;
  const float* x        = (const float*)d_in[0];
  const float* rw       = (const float*)d_in[1];
  const int*   gub_b    = (const int*)d_in[2];
  const int*   gub_s    = (const int*)d_in[3];
  const float* gub_bias = (const float*)d_in[4];
  const int*   dwn_b    = (const int*)d_in[5];
  const int*   dwn_s    = (const int*)d_in[6];
  const float* dwn_bias = (const float*)d_in[7];
  float* out = (float*)d_out;

  // ws layout (bf16 elems): xb [T,H] | act [T, E*I] | W1d [E,R1,H] | W2t [H, E*I]
  const size_t nXb  = (size_t)Ttok * Hdim;
  const size_t nAct = (size_t)Ttok * K2;
  const size_t nW1  = (size_t)E8 * R1 * Hdim;

  uint16_t* xb  = (uint16_t*)d_ws;
  uint16_t* act = xb + nXb;
  uint16_t* w1d = act + nAct;
  uint16_t* w2t = w1d + nW1;

  static int attr_set = 0;
  if (!attr_set) {
    (void)hipFuncSetAttribute((const void*)gemm1_dp_kernel,
                              hipFuncAttributeMaxDynamicSharedMemorySize, 73728);
    (void)hipFuncSetAttribute((const void*)gemm2_dp_kernel,
                              hipFuncAttributeMaxDynamicSharedMemorySize, 73728);
    attr_set = 1;
  }

  cvt_x_kernel<<<dim3((Ttok * Hdim / 4 + 255) / 256), 256, 0, stream>>>(x, xb, Ttok * Hdim);
  dq_w_kernel<<<dim3((int)((size_t)E8 * R1 * Gg / 256)), 256, 0, stream>>>(gub_b, gub_s, w1d);
  dq_w2t_kernel<<<dim3((int)((size_t)E8 * Hdim * Gg / 256)), 256, 0, stream>>>(dwn_b, dwn_s, w2t);
  bias_init_kernel<<<dim3(3, Ttok), 256, 0, stream>>>(rw, dwn_bias, out);
  gemm1_dp_kernel<<<dim3(4, 45, 8), 512, 73728, stream>>>(xb, w1d, gub_bias, rw, act);
  gemm2_dp_kernel<<<dim3(4, 23, 4), 512, 73728, stream>>>(act, w2t, out);
}

// Round 5
// 982.146 us; speedup vs baseline: 1.1773x; 1.0491x over previous
//
#include <hip/hip_runtime.h>
#include <cstdint>

// ---------------------------------------------------------------------------
// MXFP4 GPT-OSS MoE experts: dense all-expert GLU MLP.
// Round 9: (a) dq_w/dq_w2t re-coalesced: one 16B granule per thread (was 64B
// at 64B lane-stride -> sectored reads/writes). (b) gemm2 K-split 4->8: 736
// blocks = 2.87/CU so no CU runs at 1-block residency (round-7 showed 1-block
// CUs run ~2.3x slower; 368-block grid left ~112 CUs starved).
// gemm1 unchanged (313us, 870 TF, at m97-structure ceiling).
// ---------------------------------------------------------------------------

typedef float  floatx4 __attribute__((ext_vector_type(4)));
typedef __bf16 bf16x8  __attribute__((ext_vector_type(8)));

#define E8   8
#define Hdim 2880
#define Idim 2880
#define Ttok 1024
#define R1   5760   // 2*I rows of gate_up weights
#define Gg   90     // scale groups per row (K/32)
#define K2   (E8 * Idim)   // 23040 flattened (e,i) K for GEMM2

__device__ __forceinline__ void load_lds16(const void* gptr, void* lptr) {
  __builtin_amdgcn_global_load_lds(
      (const __attribute__((address_space(1))) uint32_t*)gptr,
      (__attribute__((address_space(3))) uint32_t*)lptr, 16, 0, 0);
}

__device__ __forceinline__ uint32_t f2bf(float f) {  // RTN-even fp32->bf16
  uint32_t u = __float_as_uint(f);
  return (u + 0x7FFFu + ((u >> 16) & 1u)) >> 16;
}

__device__ __forceinline__ uint32_t perm(uint32_t hi, uint32_t lo, uint32_t sel) {
  return __builtin_amdgcn_perm(hi, lo, sel);
}

// Per-scale-group LUT: bf16 bit patterns of FP4 magnitudes 0..7 scaled by
// 2^(s-127), split into low/high bytes for v_perm lookup. Entry 0 stays 0.
struct DqLut { uint32_t Ll, Lh, Hl, Hh; };

__device__ __forceinline__ DqLut make_lut(int s) {
  uint32_t A  = ((uint32_t)(s - 127) << 7) & 0xFFFFu;
  uint32_t e1 = (0x3F00u + A) & 0xFFFFu, e2 = (0x3F80u + A) & 0xFFFFu;
  uint32_t e3 = (0x3FC0u + A) & 0xFFFFu, e4 = (0x4000u + A) & 0xFFFFu;
  uint32_t e5 = (0x4040u + A) & 0xFFFFu, e6 = (0x4080u + A) & 0xFFFFu;
  uint32_t e7 = (0x40C0u + A) & 0xFFFFu;
  uint32_t B01 = e1 << 16, B23 = e2 | (e3 << 16);
  uint32_t B45 = e4 | (e5 << 16), B67 = e6 | (e7 << 16);
  DqLut L;
  L.Ll = perm(B23, B01, 0x06040200u);
  L.Hl = perm(B23, B01, 0x07050301u);
  L.Lh = perm(B67, B45, 0x06040200u);
  L.Hh = perm(B67, B45, 0x07050301u);
  return L;
}

// 4 source dwords (1 packed byte each) -> 8 bf16 (4 dwords), interleaved order.
__device__ __forceinline__ uint4 dq8(const DqLut& L, int4 wr) {
  uint32_t p = perm((uint32_t)wr.y, (uint32_t)wr.x, 0x04000400u);
  uint32_t q = perm((uint32_t)wr.w, (uint32_t)wr.z, 0x04000400u);
  uint32_t w = perm(q, p, 0x05040100u);
  uint32_t ilo = w & 0x07070707u;
  uint32_t ihi = (w >> 4) & 0x07070707u;
  uint32_t Llo = perm(L.Lh, L.Ll, ilo);
  uint32_t Hlo = perm(L.Hh, L.Hl, ilo) | ((w << 4) & 0x80808080u);
  uint32_t Lhi = perm(L.Lh, L.Ll, ihi);
  uint32_t Hhi = perm(L.Hh, L.Hl, ihi) | (w & 0x80808080u);
  uint32_t t0 = perm(Hlo, Llo, 0x05010400u);
  uint32_t t1 = perm(Hlo, Llo, 0x07030602u);
  uint32_t t2 = perm(Hhi, Lhi, 0x05010400u);
  uint32_t t3 = perm(Hhi, Lhi, 0x07030602u);
  uint4 o;
  o.x = perm(t2, t0, 0x05040100u);
  o.y = perm(t2, t0, 0x07060302u);
  o.z = perm(t3, t1, 0x05040100u);
  o.w = perm(t3, t1, 0x07060302u);
  return o;
}

// ---------------------------------------------------------------------------
__global__ void cvt_x_kernel(const float* __restrict__ x, uint16_t* __restrict__ xb, int n) {
  int i = (blockIdx.x * 256 + threadIdx.x) * 4;
  if (i >= n) return;
  float4 v = *(const float4*)(x + i);
  ushort4 o = make_ushort4((uint16_t)f2bf(v.x), (uint16_t)f2bf(v.y),
                           (uint16_t)f2bf(v.z), (uint16_t)f2bf(v.w));
  *(ushort4*)(xb + i) = o;
}

// W1 pre-dequant, coalesced: one 16B granule (4 packed words -> 8 bf16) per
// thread; 4 threads share a scale group. 16B/lane contiguous read AND write.
__global__ void dq_w_kernel(const int* __restrict__ blocks, const int* __restrict__ scales,
                            uint16_t* __restrict__ wd) {
  size_t q = (size_t)blockIdx.x * 256 + threadIdx.x;
  size_t g = q >> 2;
  int part = (int)(q & 3);
  int4 w = ((const int4*)(blocks + g * 16))[part];
  DqLut L = make_lut(scales[g]);
  *(uint4*)(wd + g * 32 + part * 8) = dq8(L, w);
}

// W2 pre-dequant TRANSPOSED + coalesced: [e][h][i] blocks -> [h][e*Idim+i].
__global__ void dq_w2t_kernel(const int* __restrict__ blocks, const int* __restrict__ scales,
                              uint16_t* __restrict__ wt) {
  size_t q = (size_t)blockIdx.x * 256 + threadIdx.x;
  size_t g = q >> 2;
  int part = (int)(q & 3);
  int e  = (int)(g / ((size_t)Hdim * Gg));
  int rm = (int)(g % ((size_t)Hdim * Gg));
  int h  = rm / Gg;
  int ig = rm % Gg;
  int4 w = ((const int4*)(blocks + g * 16))[part];
  DqLut L = make_lut(scales[g]);
  *(uint4*)(wt + ((size_t)h * E8 + e) * Idim + (size_t)ig * 32 + part * 8) = dq8(L, w);
}

// out[t,h] = sum_e rw[t,e] * down_bias[e,h]   (gemm2 atomicAdds on top)
__global__ void bias_init_kernel(const float* __restrict__ rw, const float* __restrict__ bias,
                                 float* __restrict__ out) {
  int t  = blockIdx.y;
  int h4 = (blockIdx.x * 256 + threadIdx.x) * 4;
  if (h4 >= Hdim) return;
  float4 s = make_float4(0.f, 0.f, 0.f, 0.f);
  #pragma unroll
  for (int e = 0; e < E8; ++e) {
    float w = rw[t * E8 + e];
    float4 b = *(const float4*)(bias + (size_t)e * Hdim + h4);
    s.x += w * b.x; s.y += w * b.y; s.z += w * b.z; s.w += w * b.w;
  }
  *(float4*)(out + (size_t)t * Hdim + h4) = s;
}

// ---------------------------------------------------------------------------
// GEMM1 deep-pipelined: BM=256 tokens x BN=128 f-rows x BK=32, 512 threads
// (8 waves, 4M x 2N, wave tile 64x64). LDS: 3-slot ring (A 16KB + B 8KB per
// slot = 72KB). Distance-2 prefetch; per K-step: vmcnt(3) -> s_barrier ->
// issue 3 global_load_lds for tile j+2 -> 8 ds_read_b128 -> 16 MFMA.
// Swizzle: granule p in LDS holds global granule p ^ ((row>>1)&3)  (rows are
// 64B, so fold row bits 1..2 into the 16B-slot index -> 2-way bank alias, free).
// Epilogue: GLU + bias, pre-multiply by rw[t,e], store bf16 to act[t][(e,i)].
__global__ __launch_bounds__(512) void gemm1_dp_kernel(
    const uint16_t* __restrict__ xb, const uint16_t* __restrict__ w1d,
    const float* __restrict__ bias, const float* __restrict__ rw,
    uint16_t* __restrict__ act) {
  extern __shared__ uint16_t smem[];          // 3*8192 (A) + 3*4096 (B) = 36864 elems
  uint16_t* sAr = smem;                       // [3][256*32]
  uint16_t* sBr = smem + 3 * 8192;            // [3][128*32]
  const int tid  = threadIdx.x;
  const int lane = tid & 63, wv = tid >> 6;
  const int wm = wv >> 1, wn = wv & 1;        // 4 M-waves x 2 N-waves
  const int col = lane & 15, quad = lane >> 4;
  const int e  = blockIdx.z;
  const int t0 = blockIdx.x * 256;
  const int i0 = blockIdx.y * 64;

  floatx4 acc[4][4] = {};

  // Staging sources (per-thread, pre-swizzled granule). granule = 8 elems=16B.
  // A: 256 rows x 4 granules = 1024 -> 2 issues of 512. B: 128x4 = 1 issue.
  const uint16_t* aSrc0;
  const uint16_t* aSrc1;
  const uint16_t* bSrc;
  {
    int L0 = tid;            // issue 0: rows 0..127
    int r0 = L0 >> 2;
    int g0 = (L0 & 3) ^ ((r0 >> 1) & 3);
    aSrc0 = xb + (size_t)(t0 + r0) * Hdim + g0 * 8;
    int L1 = 512 + tid;      // issue 1: rows 128..255
    int r1 = L1 >> 2;
    int g1 = (L1 & 3) ^ ((r1 >> 1) & 3);
    aSrc1 = xb + (size_t)(t0 + r1) * Hdim + g1 * 8;
    int rb = tid >> 2;       // B rows 0..127 (deinterleaved gate/up blocks)
    int gb = (tid & 3) ^ ((rb >> 1) & 3);
    int orig = 2 * (((rb >> 6) << 5) + (rb & 31)) + ((rb >> 5) & 1);
    bSrc = w1d + ((size_t)e * R1 + 2 * i0 + orig) * Hdim + gb * 8;
  }
  // Wave-uniform LDS dst offsets (elems) within a slot; DMA adds lane*16B.
  const int aOff0 = (wv * 64) * 8;
  const int aOff1 = (512 + wv * 64) * 8;
  const int bOff  = (wv * 64) * 8;

  auto STAGE = [&](int kt, int slot) {
    const int k0 = kt * 32;
    uint16_t* A = sAr + slot * 8192;
    uint16_t* B = sBr + slot * 4096;
    load_lds16(aSrc0 + k0, A + aOff0);
    load_lds16(aSrc1 + k0, A + aOff1);
    load_lds16(bSrc + k0, B + bOff);
  };

  STAGE(0, 0);
  STAGE(1, 1);

  int sr = 0;  // read slot = j % 3
  for (int j = 0; j < 90; ++j) {
    // Drain ONLY tile j (own 3 loads); tiles j+1, j+2 stay in flight.
    asm volatile("s_waitcnt vmcnt(3)" ::: "memory");
    __builtin_amdgcn_s_barrier();          // now ALL waves' tile-j DMA landed
    asm volatile("" ::: "memory");         // pin reads below the barrier
    int js = j + 2; if (js > 89) js = 89;  // clamped tail restage (harmless)
    int sw = sr + 2; if (sw >= 3) sw -= 3; // slot of tile j-1: freed last iter
    STAGE(js, sw);

    const uint16_t* A = sAr + sr * 8192;
    const uint16_t* B = sBr + sr * 4096;
    bf16x8 af[4], bfr[4];
    #pragma unroll
    for (int fm = 0; fm < 4; ++fm) {
      int row = wm * 64 + fm * 16 + col;
      int g = quad ^ ((row >> 1) & 3);
      af[fm] = *(const bf16x8*)&A[row * 32 + g * 8];
    }
    #pragma unroll
    for (int fn = 0; fn < 4; ++fn) {
      int row = wn * 64 + fn * 16 + col;
      int g = quad ^ ((row >> 1) & 3);
      bfr[fn] = *(const bf16x8*)&B[row * 32 + g * 8];
    }
    __builtin_amdgcn_s_setprio(1);
    #pragma unroll
    for (int fm = 0; fm < 4; ++fm)
      #pragma unroll
      for (int fn = 0; fn < 4; ++fn)
        acc[fm][fn] = __builtin_amdgcn_mfma_f32_16x16x32_bf16(
            af[fm], bfr[fn], acc[fm][fn], 0, 0, 0);
    __builtin_amdgcn_s_setprio(0);
    sr = (sr + 1 == 3) ? 0 : sr + 1;
  }

  #pragma unroll
  for (int fm = 0; fm < 4; ++fm) {
    #pragma unroll
    for (int p = 0; p < 2; ++p) {
      floatx4 ga = acc[fm][p], ua = acc[fm][p + 2];
      int ig = i0 + wn * 32 + p * 16 + col;
      float bg = bias[(size_t)e * R1 + 2 * ig];
      float bu = bias[(size_t)e * R1 + 2 * ig + 1];
      #pragma unroll
      for (int r = 0; r < 4; ++r) {
        int t = t0 + wm * 64 + fm * 16 + quad * 4 + r;
        float gate = fminf(ga[r] + bg, 7.0f);
        float up   = fminf(fmaxf(ua[r] + bu, -7.0f), 7.0f);
        float glu  = gate / (1.0f + __expf(-1.702f * gate));
        float a    = rw[t * E8 + e] * (up + 1.0f) * glu;
        act[((size_t)t * E8 + e) * Idim + ig] = (uint16_t)f2bf(a);
      }
    }
  }
}

// ---------------------------------------------------------------------------
// GEMM2 deep-pipelined, gemm1 geometry: M=1024 x N=2880(pad->2944) x K=23040.
// BM=256, BN=128, BK=32, K-split 8 -> grid (4,23,8)=736 blocks (2.87/CU; no
// CU runs at 1-block residency). 512 thr (8 waves, 4M x 2N, wave 64x64).
// 3-slot 72KB ring, distance-2 prefetch, vmcnt(3) + single s_barrier per
// K-step, setprio-wrapped MFMA. B staging rows clamped to h<=2879 (pad tile);
// epilogue atomicAdd guarded h<2880.
__global__ __launch_bounds__(512) void gemm2_dp_kernel(
    const uint16_t* __restrict__ actT, const uint16_t* __restrict__ w2t,
    float* __restrict__ out) {
  extern __shared__ uint16_t smem[];          // 3*8192 (A) + 3*4096 (B)
  uint16_t* sAr = smem;                       // [3][256*32]
  uint16_t* sBr = smem + 3 * 8192;            // [3][128*32]
  const int tid  = threadIdx.x;
  const int lane = tid & 63, wv = tid >> 6;
  const int wm = wv >> 1, wn = wv & 1;        // 4 M-waves x 2 N-waves
  const int col = lane & 15, quad = lane >> 4;
  const int t0 = blockIdx.x * 256;
  const int h0 = blockIdx.y * 128;            // last block: 2816..2943 (padded)
  const int kbase = blockIdx.z * (K2 / 8);    // 2880 per split

  floatx4 acc[4][4] = {};

  const uint16_t* aSrc0;
  const uint16_t* aSrc1;
  const uint16_t* bSrc;
  {
    int L0 = tid;            // A rows 0..127
    int r0 = L0 >> 2;
    int g0 = (L0 & 3) ^ ((r0 >> 1) & 3);
    aSrc0 = actT + (size_t)(t0 + r0) * K2 + kbase + g0 * 8;
    int L1 = 512 + tid;      // A rows 128..255
    int r1 = L1 >> 2;
    int g1 = (L1 & 3) ^ ((r1 >> 1) & 3);
    aSrc1 = actT + (size_t)(t0 + r1) * K2 + kbase + g1 * 8;
    int rb = tid >> 2;       // B rows 0..127 of w2t panel
    int gb = (tid & 3) ^ ((rb >> 1) & 3);
    int hb = h0 + rb; if (hb > Hdim - 1) hb = Hdim - 1;   // pad-tile clamp
    bSrc = w2t + (size_t)hb * K2 + kbase + gb * 8;
  }
  const int aOff0 = (wv * 64) * 8;
  const int aOff1 = (512 + wv * 64) * 8;
  const int bOff  = (wv * 64) * 8;

  auto STAGE = [&](int kt, int slot) {
    const int k0 = kt * 32;
    uint16_t* A = sAr + slot * 8192;
    uint16_t* B = sBr + slot * 4096;
    load_lds16(aSrc0 + k0, A + aOff0);
    load_lds16(aSrc1 + k0, A + aOff1);
    load_lds16(bSrc + k0, B + bOff);
  };

  STAGE(0, 0);
  STAGE(1, 1);

  int sr = 0;  // read slot = j % 3
  for (int j = 0; j < 90; ++j) {
    asm volatile("s_waitcnt vmcnt(3)" ::: "memory");
    __builtin_amdgcn_s_barrier();
    asm volatile("" ::: "memory");
    int js = j + 2; if (js > 89) js = 89;
    int sw = sr + 2; if (sw >= 3) sw -= 3;
    STAGE(js, sw);

    const uint16_t* A = sAr + sr * 8192;
    const uint16_t* B = sBr + sr * 4096;
    bf16x8 af[4], bfr[4];
    #pragma unroll
    for (int fm = 0; fm < 4; ++fm) {
      int row = wm * 64 + fm * 16 + col;
      int g = quad ^ ((row >> 1) & 3);
      af[fm] = *(const bf16x8*)&A[row * 32 + g * 8];
    }
    #pragma unroll
    for (int fn = 0; fn < 4; ++fn) {
      int row = wn * 64 + fn * 16 + col;
      int g = quad ^ ((row >> 1) & 3);
      bfr[fn] = *(const bf16x8*)&B[row * 32 + g * 8];
    }
    __builtin_amdgcn_s_setprio(1);
    #pragma unroll
    for (int fm = 0; fm < 4; ++fm)
      #pragma unroll
      for (int fn = 0; fn < 4; ++fn)
        acc[fm][fn] = __builtin_amdgcn_mfma_f32_16x16x32_bf16(
            af[fm], bfr[fn], acc[fm][fn], 0, 0, 0);
    __builtin_amdgcn_s_setprio(0);
    sr = (sr + 1 == 3) ? 0 : sr + 1;
  }

  #pragma unroll
  for (int fm = 0; fm < 4; ++fm)
    #pragma unroll
    for (int fn = 0; fn < 4; ++fn) {
      int h = h0 + wn * 64 + fn * 16 + col;
      if (h < Hdim) {
        #pragma unroll
        for (int r = 0; r < 4; ++r) {
          int t = t0 + wm * 64 + fm * 16 + quad * 4 + r;
          atomicAdd(out + (size_t)t * Hdim + h, acc[fm][fn][r]);
        }
      }
    }
}

// ---------------------------------------------------------------------------
extern "C" void kernel_launch(void* const* d_in, const int* in_sizes, int n_in,
                              void* d_out, int out_size, void* d_ws, size_t ws_size,
                              hipStream_t stream) {
  (void)in_sizes; (void)n_in; (void)out_size; (void)ws_size;
  const float* x        = (const float*)d_in[0];
  const float* rw       = (const float*)d_in[1];
  const int*   gub_b    = (const int*)d_in[2];
  const int*   gub_s    = (const int*)d_in[3];
  const float* gub_bias = (const float*)d_in[4];
  const int*   dwn_b    = (const int*)d_in[5];
  const int*   dwn_s    = (const int*)d_in[6];
  const float* dwn_bias = (const float*)d_in[7];
  float* out = (float*)d_out;

  // ws layout (bf16 elems): xb [T,H] | act [T, E*I] | W1d [E,R1,H] | W2t [H, E*I]
  const size_t nXb  = (size_t)Ttok * Hdim;
  const size_t nAct = (size_t)Ttok * K2;
  const size_t nW1  = (size_t)E8 * R1 * Hdim;

  uint16_t* xb  = (uint16_t*)d_ws;
  uint16_t* act = xb + nXb;
  uint16_t* w1d = act + nAct;
  uint16_t* w2t = w1d + nW1;

  static int attr_set = 0;
  if (!attr_set) {
    (void)hipFuncSetAttribute((const void*)gemm1_dp_kernel,
                              hipFuncAttributeMaxDynamicSharedMemorySize, 73728);
    (void)hipFuncSetAttribute((const void*)gemm2_dp_kernel,
                              hipFuncAttributeMaxDynamicSharedMemorySize, 73728);
    attr_set = 1;
  }

  cvt_x_kernel<<<dim3((Ttok * Hdim / 4 + 255) / 256), 256, 0, stream>>>(x, xb, Ttok * Hdim);
  dq_w_kernel<<<dim3((int)((size_t)E8 * R1 * Gg * 4 / 256)), 256, 0, stream>>>(gub_b, gub_s, w1d);
  dq_w2t_kernel<<<dim3((int)((size_t)E8 * Hdim * Gg * 4 / 256)), 256, 0, stream>>>(dwn_b, dwn_s, w2t);
  bias_init_kernel<<<dim3(3, Ttok), 256, 0, stream>>>(rw, dwn_bias, out);
  gemm1_dp_kernel<<<dim3(4, 45, 8), 512, 73728, stream>>>(xb, w1d, gub_bias, rw, act);
  gemm2_dp_kernel<<<dim3(4, 23, 8), 512, 73728, stream>>>(act, w2t, out);
}